// Round 10
// baseline (37.900 us; speedup 1.0000x reference)
//
#include <hip/hip_runtime.h>
#include <math.h>

#define SF 0.99999f
#define PI2 6.283185307179586476925f
#define SWZ(c) ((c) ^ (((c) >> 4) & 15))
// compiler-only fence: orders same-wave LDS write/read phases (HW LDS pipe is
// in-order per wave; this stops compiler reordering).
#define LDSFENCE() asm volatile("" ::: "memory")

template<int SGN>
__device__ __forceinline__ void twmul(float& ur, float& ui, float c, float s) {
    const float ss = (SGN < 0) ? -s : s;
    const float r = ur * c - ui * ss;
    const float i = ui * c + ur * ss;
    ur = r; ui = i;
}

// 8-point DFT across registers. SGN=-1: forward; SGN=+1: inverse.
template<int SGN>
__device__ __forceinline__ void bfly8(float* ur, float* ui) {
    const float C2 = 0.70710678118654752440f;
    float ar[4], ai[4], br[4], bi[4];
#pragma unroll
    for (int m = 0; m < 4; ++m) {
        ar[m] = ur[m] + ur[m + 4]; ai[m] = ui[m] + ui[m + 4];
        br[m] = ur[m] - ur[m + 4]; bi[m] = ui[m] - ui[m + 4];
    }
    float b1r, b1i, b2r, b2i, b3r, b3i;
    if (SGN < 0) {
        b1r = C2 * (br[1] + bi[1]); b1i = C2 * (bi[1] - br[1]);
        b2r = bi[2];                b2i = -br[2];
        b3r = C2 * (bi[3] - br[3]); b3i = -C2 * (br[3] + bi[3]);
    } else {
        b1r = C2 * (br[1] - bi[1]); b1i = C2 * (bi[1] + br[1]);
        b2r = -bi[2];               b2i = br[2];
        b3r = -C2 * (br[3] + bi[3]); b3i = C2 * (br[3] - bi[3]);
    }
    const float e0r = ar[0] + ar[2], e0i = ai[0] + ai[2];
    const float e1r = ar[0] - ar[2], e1i = ai[0] - ai[2];
    const float o0r = ar[1] + ar[3], o0i = ai[1] + ai[3];
    const float o1r = ar[1] - ar[3], o1i = ai[1] - ai[3];
    ur[0] = e0r + o0r; ui[0] = e0i + o0i;
    ur[4] = e0r - o0r; ui[4] = e0i - o0i;
    if (SGN < 0) { ur[2] = e1r + o1i; ui[2] = e1i - o1r; ur[6] = e1r - o1i; ui[6] = e1i + o1r; }
    else         { ur[2] = e1r - o1i; ui[2] = e1i + o1r; ur[6] = e1r + o1i; ui[6] = e1i - o1r; }
    const float f0r = br[0] + b2r, f0i = bi[0] + b2i;
    const float f1r = br[0] - b2r, f1i = bi[0] - b2i;
    const float g0r = b1r + b3r, g0i = b1i + b3i;
    const float g1r = b1r - b3r, g1i = b1i - b3i;
    ur[1] = f0r + g0r; ui[1] = f0i + g0i;
    ur[5] = f0r - g0r; ui[5] = f0i - g0i;
    if (SGN < 0) { ur[3] = f1r + g1i; ui[3] = f1i - g1r; ur[7] = f1r - g1i; ui[7] = f1i + g1r; }
    else         { ur[3] = f1r - g1i; ui[3] = f1i + g1r; ur[7] = f1r + g1i; ui[7] = f1i - g1r; }
}

// Wave-local 512-pt complex FFT, Stockham radix-8, 3 stages, single LDS buffer.
// ra[8] = hoisted read indices SWZ(t+64m). Writes per-element inline SWZ.
// No barriers.
template<int SGN>
__device__ __forceinline__ void fft512w(float* ur, float* ui,
                                        float2* __restrict__ buf,
                                        const float2* __restrict__ tw2,
                                        const float2* __restrict__ tw3,
                                        const int* ra, int t) {
    bfly8<SGN>(ur, ui);
    LDSFENCE();
#pragma unroll
    for (int m = 0; m < 8; ++m) buf[SWZ(8 * t + m)] = make_float2(ur[m], ui[m]);
    LDSFENCE();
#pragma unroll
    for (int m = 0; m < 8; ++m) { const float2 v = buf[ra[m]]; ur[m] = v.x; ui[m] = v.y; }
    const int k2 = t & 7;
#pragma unroll
    for (int m = 1; m < 8; ++m) { const float2 w = tw2[m * 8 + k2]; twmul<SGN>(ur[m], ui[m], w.x, w.y); }
    bfly8<SGN>(ur, ui);
    const int jj = ((t >> 3) << 6) + k2;
    LDSFENCE();
#pragma unroll
    for (int m = 0; m < 8; ++m) buf[SWZ(jj + 8 * m)] = make_float2(ur[m], ui[m]);
    LDSFENCE();
#pragma unroll
    for (int m = 0; m < 8; ++m) { const float2 v = buf[ra[m]]; ur[m] = v.x; ui[m] = v.y; }
#pragma unroll
    for (int m = 1; m < 8; ++m) { const float2 w = tw3[m * 64 + t]; twmul<SGN>(ur[m], ui[m], w.x, w.y); }
    bfly8<SGN>(ur, ui);
    LDSFENCE();
}

// Two independent 512-pt FFTs interleaved through two buffers: shared stall
// windows, 2x VALU per LDS wait, half the serial windows of two calls.
template<int SGN>
__device__ __forceinline__ void fft512w_dual(float* urA, float* uiA,
                                             float* urB, float* uiB,
                                             float2* __restrict__ bufA,
                                             float2* __restrict__ bufB,
                                             const float2* __restrict__ tw2,
                                             const float2* __restrict__ tw3,
                                             const int* ra, int t) {
    bfly8<SGN>(urA, uiA);
    bfly8<SGN>(urB, uiB);
    LDSFENCE();
#pragma unroll
    for (int m = 0; m < 8; ++m) bufA[SWZ(8 * t + m)] = make_float2(urA[m], uiA[m]);
#pragma unroll
    for (int m = 0; m < 8; ++m) bufB[SWZ(8 * t + m)] = make_float2(urB[m], uiB[m]);
    LDSFENCE();
#pragma unroll
    for (int m = 0; m < 8; ++m) { const float2 v = bufA[ra[m]]; urA[m] = v.x; uiA[m] = v.y; }
#pragma unroll
    for (int m = 0; m < 8; ++m) { const float2 v = bufB[ra[m]]; urB[m] = v.x; uiB[m] = v.y; }
    const int k2 = t & 7;
#pragma unroll
    for (int m = 1; m < 8; ++m) {
        const float2 wv = tw2[m * 8 + k2];
        twmul<SGN>(urA[m], uiA[m], wv.x, wv.y);
        twmul<SGN>(urB[m], uiB[m], wv.x, wv.y);
    }
    bfly8<SGN>(urA, uiA);
    bfly8<SGN>(urB, uiB);
    const int jj = ((t >> 3) << 6) + k2;
    LDSFENCE();
#pragma unroll
    for (int m = 0; m < 8; ++m) bufA[SWZ(jj + 8 * m)] = make_float2(urA[m], uiA[m]);
#pragma unroll
    for (int m = 0; m < 8; ++m) bufB[SWZ(jj + 8 * m)] = make_float2(urB[m], uiB[m]);
    LDSFENCE();
#pragma unroll
    for (int m = 0; m < 8; ++m) { const float2 v = bufA[ra[m]]; urA[m] = v.x; uiA[m] = v.y; }
#pragma unroll
    for (int m = 0; m < 8; ++m) { const float2 v = bufB[ra[m]]; urB[m] = v.x; uiB[m] = v.y; }
#pragma unroll
    for (int m = 1; m < 8; ++m) {
        const float2 wv = tw3[m * 64 + t];
        twmul<SGN>(urA[m], uiA[m], wv.x, wv.y);
        twmul<SGN>(urB[m], uiB[m], wv.x, wv.y);
    }
    bfly8<SGN>(urA, uiA);
    bfly8<SGN>(urB, uiB);
    LDSFENCE();
}

__global__ __launch_bounds__(256, 2) void pbfd_kernel(
    const float* __restrict__ g_mic,   // (B,256)
    const float* __restrict__ g_lsb,   // (B,1280)
    const float* __restrict__ g_phie,  // (B,257)
    const float* __restrict__ g_p1,    // (B,257,4)
    const float* __restrict__ g_hr,    // (B,257,4)
    const float* __restrict__ g_hi,    // (B,257,4)
    float* __restrict__ g_out,         // (B,256)
    int B) {
    __shared__ float2 tw2[64];
    __shared__ float2 tw3[512];
    __shared__ float2 xch[4][2][512];  // two exchange buffers per wave (dual FFT)

    const int tid = threadIdx.x;
    for (int e = tid; e < 512; e += 256) {
        const int m = e >> 6, tt = e & 63;
        float s, c;
        sincosf(PI2 * (float)(m * tt) * (1.0f / 512.0f), &s, &c);
        tw3[e] = make_float2(c, s);
    }
    if (tid < 64) {
        const int m = tid >> 3, k = tid & 7;
        float s, c;
        sincosf(PI2 * (float)(m * k) * (1.0f / 64.0f), &s, &c);
        tw2[tid] = make_float2(c, s);
    }
    __syncthreads();  // the only barrier

    const int w = tid >> 6;
    const int t = tid & 63;
    const int elem = blockIdx.x * 4 + w;
    if (elem >= B) return;
    float2* bufA = &xch[w][0][0];
    float2* bufB = &xch[w][1][0];
    const int ml = (64 - t) & 63;  // mirror lane: bin 512-k lives at (ml, 7-m) for t>=1

    // ---- hoisted LDS read indices (invariant across all FFTs) ----
    int ra[8];
#pragma unroll
    for (int m = 0; m < 8; ++m) ra[m] = SWZ(t + 64 * m);

    float mv[4];
    {
        const float* mp = g_mic + (size_t)elem * 256;
#pragma unroll
        for (int q = 0; q < 4; ++q) mv[q] = mp[t + 64 * q];
    }

    // ---- X: 4 real frame-FFTs as one DUAL packed complex FFT ----
    float xr[4][4], xi[4][4], xn[4];
    {
        const float* lb = g_lsb + (size_t)elem * 1280;
        float urA[8], uiA[8], urB[8], uiB[8];
#pragma unroll
        for (int m = 0; m < 8; ++m) {
            urA[m] = lb[t + 64 * m];         // frame 0
            uiA[m] = lb[256 + t + 64 * m];   // frame 1
            urB[m] = lb[512 + t + 64 * m];   // frame 2
            uiB[m] = lb[768 + t + 64 * m];   // frame 3
        }
        fft512w_dual<-1>(urA, uiA, urB, uiB, bufA, bufB, tw2, tw3, ra, t);
#pragma unroll
        for (int m = 0; m < 4; ++m) {
            float zmr = __shfl(urA[7 - m], ml);
            float zmi = __shfl(uiA[7 - m], ml);
            if (t == 0) { zmr = (m == 0) ? urA[0] : urA[8 - m]; zmi = (m == 0) ? uiA[0] : uiA[8 - m]; }
            xr[0][m] = 0.5f * (urA[m] + zmr);
            xi[0][m] = 0.5f * (uiA[m] - zmi);
            xr[1][m] = 0.5f * (uiA[m] + zmi);
            xi[1][m] = -0.5f * (urA[m] - zmr);
        }
#pragma unroll
        for (int m = 0; m < 4; ++m) {
            float zmr = __shfl(urB[7 - m], ml);
            float zmi = __shfl(uiB[7 - m], ml);
            if (t == 0) { zmr = (m == 0) ? urB[0] : urB[8 - m]; zmi = (m == 0) ? uiB[0] : uiB[8 - m]; }
            xr[2][m] = 0.5f * (urB[m] + zmr);
            xi[2][m] = 0.5f * (uiB[m] - zmi);
            xr[3][m] = 0.5f * (uiB[m] + zmi);
            xi[3][m] = -0.5f * (urB[m] - zmr);
        }
        if (t == 0) { xn[0] = urA[4]; xn[1] = uiA[4]; xn[2] = urB[4]; xn[3] = uiB[4]; }
    }

    // Hermitian IFFT of a low-half spectrum (cr/ci low slots + lane0 Nyquist cn):
    // o4[q] = Re(ifft)[256+t+64q]/512.
    auto herm_ifft = [&](const float cr[4], const float ci[4], float cn, float o4[4]) {
        float ur[8], ui[8];
#pragma unroll
        for (int m = 0; m < 4; ++m) { ur[m] = cr[m]; ui[m] = ci[m]; }
#pragma unroll
        for (int m = 4; m < 8; ++m) {
            ur[m] = __shfl(cr[7 - m], ml);
            ui[m] = -__shfl(ci[7 - m], ml);
        }
        if (t == 0) {
            ur[5] = cr[3]; ui[5] = -ci[3];
            ur[6] = cr[2]; ui[6] = -ci[2];
            ur[7] = cr[1]; ui[7] = -ci[1];
            ur[4] = cn; ui[4] = 0.f;
        }
        fft512w<1>(ur, ui, bufA, tw2, tw3, ra, t);
#pragma unroll
        for (int q = 0; q < 4; ++q) o4[q] = ur[4 + q] * (1.0f / 512.0f);
    };

    // ---- est (H prior): C = sum_j X*H; d = mic - est.  H dies after this block. ----
    float d4[4];
    float pn[4], en = 0.f, pen = 0.f;  // lane0 side channel
    {
        float hr_[4][4], hi_[4][4], hn[4];
        {
            const float4* hr4 = (const float4*)g_hr + (size_t)elem * 257;
            const float4* hi4 = (const float4*)g_hi + (size_t)elem * 257;
#pragma unroll
            for (int m = 0; m < 4; ++m) {
                const float4 a = hr4[t + 64 * m];
                hr_[0][m] = a.x; hr_[1][m] = a.y; hr_[2][m] = a.z; hr_[3][m] = a.w;
            }
#pragma unroll
            for (int m = 0; m < 4; ++m) {
                const float4 b = hi4[t + 64 * m];
                hi_[0][m] = b.x; hi_[1][m] = b.y; hi_[2][m] = b.z; hi_[3][m] = b.w;
            }
            if (t == 0) {
                const float4 a = hr4[256];
                const float4 p = ((const float4*)g_p1)[(size_t)elem * 257 + 256];
                hn[0] = a.x; hn[1] = a.y; hn[2] = a.z; hn[3] = a.w;
                pn[0] = p.x; pn[1] = p.y; pn[2] = p.z; pn[3] = p.w;
            }
        }
        float cr[4], ci[4], cn = 0.f;
#pragma unroll
        for (int m = 0; m < 4; ++m) {
            float sr = 0.f, si = 0.f;
#pragma unroll
            for (int j = 0; j < 4; ++j) {
                sr += xr[j][m] * hr_[j][m] - xi[j][m] * hi_[j][m];
                si += xr[j][m] * hi_[j][m] + xi[j][m] * hr_[j][m];
            }
            cr[m] = sr; ci[m] = si;
        }
        if (t == 0) {
#pragma unroll
            for (int j = 0; j < 4; ++j) cn += xn[j] * hn[j];
        }
        float o4[4];
        herm_ifft(cr, ci, cn, o4);
#pragma unroll
        for (int q = 0; q < 4; ++q) d4[q] = mv[q] - o4[q];
    }

    // ---- E = FFT([zeros(256); d]) ----
    float er[4], ei[4];
    {
        float ur[8], ui[8];
#pragma unroll
        for (int m = 0; m < 4; ++m) { ur[m] = 0.f; ui[m] = 0.f; }
#pragma unroll
        for (int q = 0; q < 4; ++q) { ur[4 + q] = d4[q]; ui[4 + q] = 0.f; }
        fft512w<-1>(ur, ui, bufA, tw2, tw3, ra, t);
#pragma unroll
        for (int m = 0; m < 4; ++m) { er[m] = ur[m]; ei[m] = ui[m]; }
        if (t == 0) en = ur[4];
    }

    // ---- phi_e ----
    float pe[4];
    {
        const float* php = g_phie + (size_t)elem * 257;
#pragma unroll
        for (int m = 0; m < 4; ++m)
            pe[m] = 0.7f * php[t + 64 * m] + 0.3f * (er[m] * er[m] + ei[m] * ei[m]);
        if (t == 0) pen = 0.7f * php[256] + 0.3f * en * en;
    }

    // ---- gradient, fully dual: A = KE0+i*KE1, B = KE2+i*KE3;
    //      dual-IFFT -> mask -> dual-FFT -> unpack, accumulating D = sum X*fd_dH ----
    float Dr[4] = {0, 0, 0, 0}, Di[4] = {0, 0, 0, 0};
    float dn = 0.f;  // lane0: D at Nyquist
    {
        const float4* p14 = (const float4*)g_p1 + (size_t)elem * 257;
        float urA[8], uiA[8], urB[8], uiB[8];
        // --- pair A (partitions 0,1): KE, then mirror-extend immediately (gr dies) ---
        {
            float gr[4], gi[4];
#pragma unroll
            for (int m = 0; m < 4; ++m) {
                const float4 p = p14[t + 64 * m];
                const float xx0 = xr[0][m] * xr[0][m] + xi[0][m] * xi[0][m];
                const float R0 = xx0 * p.x + 2.f * pe[m] + 1e-10f;
                const float i0 = 1.f / R0;
                const float kr0 = p.x * xr[0][m] * i0, ki0 = -p.x * xi[0][m] * i0;
                const float a_r = kr0 * er[m] - ki0 * ei[m];
                const float a_i = kr0 * ei[m] + ki0 * er[m];
                const float xx1 = xr[1][m] * xr[1][m] + xi[1][m] * xi[1][m];
                const float R1 = xx1 * p.y + 2.f * pe[m] + 1e-10f;
                const float i1 = 1.f / R1;
                const float kr1 = p.y * xr[1][m] * i1, ki1 = -p.y * xi[1][m] * i1;
                const float b_r = kr1 * er[m] - ki1 * ei[m];
                const float b_i = kr1 * ei[m] + ki1 * er[m];
                urA[m] = a_r - b_i;  uiA[m] = a_i + b_r;
                gr[m] = a_r + b_i;   gi[m] = b_r - a_i;
            }
#pragma unroll
            for (int m = 4; m < 8; ++m) {
                urA[m] = __shfl(gr[7 - m], ml);
                uiA[m] = __shfl(gi[7 - m], ml);
            }
            if (t == 0) {
                urA[5] = gr[3]; uiA[5] = gi[3];
                urA[6] = gr[2]; uiA[6] = gi[2];
                urA[7] = gr[1]; uiA[7] = gi[1];
                const float Rn0 = xn[0] * xn[0] * pn[0] + 2.f * pen + 1e-10f;
                const float Rn1 = xn[1] * xn[1] * pn[1] + 2.f * pen + 1e-10f;
                urA[4] = pn[0] * xn[0] / Rn0 * en;
                uiA[4] = pn[1] * xn[1] / Rn1 * en;
            }
        }
        // --- pair B (partitions 2,3) ---
        {
            float gr[4], gi[4];
#pragma unroll
            for (int m = 0; m < 4; ++m) {
                const float4 p = p14[t + 64 * m];
                const float xx2 = xr[2][m] * xr[2][m] + xi[2][m] * xi[2][m];
                const float R2 = xx2 * p.z + 2.f * pe[m] + 1e-10f;
                const float i2 = 1.f / R2;
                const float kr2 = p.z * xr[2][m] * i2, ki2 = -p.z * xi[2][m] * i2;
                const float c_r = kr2 * er[m] - ki2 * ei[m];
                const float c_i = kr2 * ei[m] + ki2 * er[m];
                const float xx3 = xr[3][m] * xr[3][m] + xi[3][m] * xi[3][m];
                const float R3 = xx3 * p.w + 2.f * pe[m] + 1e-10f;
                const float i3 = 1.f / R3;
                const float kr3 = p.w * xr[3][m] * i3, ki3 = -p.w * xi[3][m] * i3;
                const float d_r = kr3 * er[m] - ki3 * ei[m];
                const float d_i = kr3 * ei[m] + ki3 * er[m];
                urB[m] = c_r - d_i;  uiB[m] = c_i + d_r;
                gr[m] = c_r + d_i;   gi[m] = d_r - c_i;
            }
#pragma unroll
            for (int m = 4; m < 8; ++m) {
                urB[m] = __shfl(gr[7 - m], ml);
                uiB[m] = __shfl(gi[7 - m], ml);
            }
            if (t == 0) {
                urB[5] = gr[3]; uiB[5] = gi[3];
                urB[6] = gr[2]; uiB[6] = gi[2];
                urB[7] = gr[1]; uiB[7] = gi[1];
                const float Rn2 = xn[2] * xn[2] * pn[2] + 2.f * pen + 1e-10f;
                const float Rn3 = xn[3] * xn[3] * pn[3] + 2.f * pen + 1e-10f;
                urB[4] = pn[2] * xn[2] / Rn2 * en;
                uiB[4] = pn[3] * xn[3] / Rn3 * en;
            }
        }
        fft512w_dual<1>(urA, uiA, urB, uiB, bufA, bufB, tw2, tw3, ra, t);  // 512*dH pairs
        // mask n<256 (slots m<4), scale 1/512
#pragma unroll
        for (int m = 0; m < 4; ++m) {
            urA[m] *= (1.0f / 512.0f); uiA[m] *= (1.0f / 512.0f);
            urB[m] *= (1.0f / 512.0f); uiB[m] *= (1.0f / 512.0f);
        }
#pragma unroll
        for (int m = 4; m < 8; ++m) {
            urA[m] = 0.f; uiA[m] = 0.f;
            urB[m] = 0.f; uiB[m] = 0.f;
        }
        fft512w_dual<-1>(urA, uiA, urB, uiB, bufA, bufB, tw2, tw3, ra, t);  // fd_dH pairs
        // unpack low slots: fd0 = (Z+conj(Zm))/2, fd1 = -i/2 (Z-conj(Zm)); D += X*fd
#pragma unroll
        for (int m = 0; m < 4; ++m) {
            float zmr = __shfl(urA[7 - m], ml);
            float zmi = __shfl(uiA[7 - m], ml);
            if (t == 0) { zmr = (m == 0) ? urA[0] : urA[8 - m]; zmi = (m == 0) ? uiA[0] : uiA[8 - m]; }
            const float f0r = 0.5f * (urA[m] + zmr), f0i = 0.5f * (uiA[m] - zmi);
            const float f1r = 0.5f * (uiA[m] + zmi), f1i = -0.5f * (urA[m] - zmr);
            Dr[m] += xr[0][m] * f0r - xi[0][m] * f0i + xr[1][m] * f1r - xi[1][m] * f1i;
            Di[m] += xr[0][m] * f0i + xi[0][m] * f0r + xr[1][m] * f1i + xi[1][m] * f1r;
        }
#pragma unroll
        for (int m = 0; m < 4; ++m) {
            float zmr = __shfl(urB[7 - m], ml);
            float zmi = __shfl(uiB[7 - m], ml);
            if (t == 0) { zmr = (m == 0) ? urB[0] : urB[8 - m]; zmi = (m == 0) ? uiB[0] : uiB[8 - m]; }
            const float f0r = 0.5f * (urB[m] + zmr), f0i = 0.5f * (uiB[m] - zmi);
            const float f1r = 0.5f * (uiB[m] + zmi), f1i = -0.5f * (urB[m] - zmr);
            Dr[m] += xr[2][m] * f0r - xi[2][m] * f0i + xr[3][m] * f1r - xi[3][m] * f1i;
            Di[m] += xr[2][m] * f0i + xi[2][m] * f0r + xr[3][m] * f1i + xi[3][m] * f1r;
        }
        if (t == 0)
            dn = xn[0] * urA[4] + xn[1] * uiA[4] + xn[2] * urB[4] + xn[3] * uiB[4];
    }

    // ---- enhanced = mic - SF*(est + irfft(D)[256:]) ;  est = mic - d ----
    {
        float o4[4];
        herm_ifft(Dr, Di, dn, o4);
        float* op = g_out + (size_t)elem * 256;
#pragma unroll
        for (int q = 0; q < 4; ++q)
            op[t + 64 * q] = mv[q] - SF * ((mv[q] - d4[q]) + o4[q]);
    }
}

extern "C" void kernel_launch(void* const* d_in, const int* in_sizes, int n_in,
                              void* d_out, int out_size, void* d_ws, size_t ws_size,
                              hipStream_t stream) {
    const float* mic  = (const float*)d_in[0];
    const float* lsb  = (const float*)d_in[1];
    const float* phie = (const float*)d_in[2];
    // d_in[3] = phi_f: dead for the 'enhanced' output
    const float* p1   = (const float*)d_in[4];
    const float* hr   = (const float*)d_in[5];
    const float* hi   = (const float*)d_in[6];
    float* out = (float*)d_out;

    const int B = in_sizes[0] / 256;  // N_MIC == 1
    const int blocks = (B + 3) / 4;   // 4 elements (waves) per 256-thread block
    pbfd_kernel<<<blocks, 256, 0, stream>>>(mic, lsb, phie, p1, hr, hi, out, B);
}